// Round 13
// baseline (21.027 us; speedup 1.0000x reference)
//
#include <hip/hip_runtime.h>
#include <math.h>

typedef __attribute__((ext_vector_type(8))) short short8v;
typedef __attribute__((ext_vector_type(4))) float f32x4;

#define BLOCK 256
#define GRID  1024

__device__ inline unsigned int pk_bf16(float lo, float hi) {
    unsigned int r;
    asm("v_cvt_pk_bf16_f32 %0, %1, %2" : "=v"(r) : "v"(lo), "v"(hi));
    return r;
}
__device__ inline short8v as_s8(uint4 v) { union { uint4 u; short8v s; } c; c.u = v; return c.s; }
__device__ inline f32x4 as_f4(float4 v) { union { float4 u; f32x4 s; } c; c.u = v; return c.s; }

__global__ __launch_bounds__(BLOCK, 2) void bnet(
    const float* __restrict__ x,
    const float* __restrict__ meanp, const float* __restrict__ stdp,
    const float* __restrict__ W1,  const float* __restrict__ b1,
    const float* __restrict__ W21, const float* __restrict__ b21,
    const float* __restrict__ W22, const float* __restrict__ b22,
    const float* __restrict__ W31, const float* __restrict__ b31,
    const float* __restrict__ W32, const float* __restrict__ b32,
    const float* __restrict__ obstacles,
    float* __restrict__ out, int nB)
{
    // Layer-1 A-frags: [g*64+lane]; lanes<16 hold W1 row 16g+m (k=0..4 w, k=5 b1).
    __shared__ uint4 w1frag[8 * 64];                  // 8 KB
    // Layer-2 A-frags with pi-permuted K (verified rounds 4..12).
    __shared__ uint4 fragB[16 * 64];                  // 16 KB
    // Head A-frags (verified round 6/9/12): sigma-permuted W31/W32 rows.
    __shared__ uint4 headA[2 * 64];                   // 2 KB
    __shared__ float b2s[64];                         // b21[32] | b22[32]

    const int t = threadIdx.x;

    {   // zero w1frag (lanes >=16 must be zero)
        uint4 z = {0u, 0u, 0u, 0u};
        w1frag[t] = z; w1frag[t + 256] = z;
    }
    __syncthreads();
    if (t < 128) {   // W1 fragments
        int m = t & 15, g = t >> 4;
        int u = 16 * g + m;
        const float* wr = W1 + u * 5;
        uint4 v;
        v.x = pk_bf16(wr[0], wr[1]);
        v.y = pk_bf16(wr[2], wr[3]);
        v.z = pk_bf16(wr[4], b1[u]);
        v.w = 0u;
        w1frag[g * 64 + m] = v;
    } else {         // head A-fragments (threads 128..255) - round 6 verified
        int e  = t - 128;
        int ks = e >> 6, l = e & 63, m = l & 15, qq = l >> 4;
        float v[8];
        #pragma unroll
        for (int j = 0; j < 8; ++j) {
            int u = 16 * ((j >> 2) & 1) + 4 * qq + (j & 3);   // sigma^-1
            float val = 0.f;
            if (m == 0 && ks == 0) val = W31[u];
            if (m == 1 && ks == 0) val = W31[32 + u];
            if (m == 2 && ks == 1) val = W32[u];
            if (m == 3 && ks == 1) val = W32[32 + u];
            v[j] = val;
        }
        uint4 h;
        h.x = pk_bf16(v[0], v[1]); h.y = pk_bf16(v[2], v[3]);
        h.z = pk_bf16(v[4], v[5]); h.w = pk_bf16(v[6], v[7]);
        headA[ks * 64 + l] = h;
    }
    if (t < 64) b2s[t] = (t < 32) ? b21[t] : b22[t - 32];
    {   // layer-2 fragments (verified mapping)
        const float4* w21v = (const float4*)W21;
        const float4* w22v = (const float4*)W22;
        #pragma unroll
        for (int e = 0; e < 4; ++e) {
            int g4   = t + e * 256;
            int uo   = g4 >> 5;
            int h0   = (g4 & 31) << 2;
            int ks   = h0 >> 5;
            int jh   = (h0 >> 4) & 1;
            int qq   = (h0 >> 2) & 3;
            int ln   = (qq << 4) | (uo & 15);
            int half = uo >> 4;
            float4 f1 = w21v[g4];
            float4 f2 = w22v[g4];
            unsigned int* dA = (unsigned int*)&fragB[(half * 4 + ks) * 64 + ln];
            unsigned int* dB = (unsigned int*)&fragB[(8 + half * 4 + ks) * 64 + ln];
            dA[jh * 2] = pk_bf16(f1.x, f1.y); dA[jh * 2 + 1] = pk_bf16(f1.z, f1.w);
            dB[jh * 2] = pk_bf16(f2.x, f2.y); dB[jh * 2 + 1] = pk_bf16(f2.z, f2.w);
        }
    }
    __syncthreads();

    const int lane = t & 63;
    const int q    = lane >> 4;
    const int r15  = lane & 15;
    const int wid    = blockIdx.x * 4 + (t >> 6);
    const int nwaves = GRID * 4;
    const int npairs = (nB + 31) >> 5;
    if (wid >= npairs) return;

    // Resident: W2 fragments (64 VGPR) + head A-frags (8 VGPR).
    short8v bfr[16];
    #pragma unroll
    for (int i = 0; i < 16; ++i) bfr[i] = as_s8(fragB[i * 64 + lane]);
    const short8v hA0 = as_s8(headA[lane]);
    const short8v hA1 = as_s8(headA[64 + lane]);
    const float4* b2v = (const float4*)b2s;

    const float hb0 = b31[0], hb1 = b31[1], hb2 = b32[0], hb3 = b32[1];

    // Full MLP for a 32-row pair: x (per-lane rows r15 / 16+r15) -> heads.
    // Heads for rows 0..15 of each chain land on lanes 0..15 as f32x4.
    auto MLP = [&](const float xA[5], const float xB[5], f32x4& hdA, f32x4& hdB) {
        uint4 va, vb;
        va.x = pk_bf16(xA[0], xA[1]); va.y = pk_bf16(xA[2], xA[3]);
        va.z = pk_bf16(xA[4], 1.0f);  va.w = 0u;
        vb.x = pk_bf16(xB[0], xB[1]); vb.y = pk_bf16(xB[2], xB[3]);
        vb.z = pk_bf16(xB[4], 1.0f);  vb.w = 0u;
        short8v xfA = as_s8(va), xfB = as_s8(vb);

        // layer 1: 16 MFMA (2 chains), relu+pack fused
        short8v afA[4], afB[4];
        #pragma unroll
        for (int ks = 0; ks < 4; ++ks) {
            f32x4 z = {0.f, 0.f, 0.f, 0.f};
            short8v w0  = as_s8(w1frag[(2 * ks) * 64 + lane]);
            short8v w1v = as_s8(w1frag[(2 * ks + 1) * 64 + lane]);
            f32x4 hA0_ = __builtin_amdgcn_mfma_f32_16x16x32_bf16(w0,  xfA, z, 0, 0, 0);
            f32x4 hA1_ = __builtin_amdgcn_mfma_f32_16x16x32_bf16(w1v, xfA, z, 0, 0, 0);
            f32x4 hB0_ = __builtin_amdgcn_mfma_f32_16x16x32_bf16(w0,  xfB, z, 0, 0, 0);
            f32x4 hB1_ = __builtin_amdgcn_mfma_f32_16x16x32_bf16(w1v, xfB, z, 0, 0, 0);
            uint4 pa, pb;
            pa.x = pk_bf16(fmaxf(hA0_[0], 0.f), fmaxf(hA0_[1], 0.f));
            pa.y = pk_bf16(fmaxf(hA0_[2], 0.f), fmaxf(hA0_[3], 0.f));
            pa.z = pk_bf16(fmaxf(hA1_[0], 0.f), fmaxf(hA1_[1], 0.f));
            pa.w = pk_bf16(fmaxf(hA1_[2], 0.f), fmaxf(hA1_[3], 0.f));
            pb.x = pk_bf16(fmaxf(hB0_[0], 0.f), fmaxf(hB0_[1], 0.f));
            pb.y = pk_bf16(fmaxf(hB0_[2], 0.f), fmaxf(hB0_[3], 0.f));
            pb.z = pk_bf16(fmaxf(hB1_[0], 0.f), fmaxf(hB1_[1], 0.f));
            pb.w = pk_bf16(fmaxf(hB1_[2], 0.f), fmaxf(hB1_[3], 0.f));
            afA[ks] = as_s8(pa); afB[ks] = as_s8(pb);
        }

        // layer 2: 32 MFMA, bias-initialized accumulators (LDS broadcast)
        f32x4 a21aA = as_f4(b2v[q]);
        f32x4 a21bA = as_f4(b2v[4 + q]);
        f32x4 a22aA = as_f4(b2v[8 + q]);
        f32x4 a22bA = as_f4(b2v[12 + q]);
        f32x4 a21aB = a21aA, a21bB = a21bA, a22aB = a22aA, a22bB = a22bA;
        #pragma unroll
        for (int ks = 0; ks < 4; ++ks) {
            a21aA = __builtin_amdgcn_mfma_f32_16x16x32_bf16(bfr[     ks], afA[ks], a21aA, 0, 0, 0);
            a21aB = __builtin_amdgcn_mfma_f32_16x16x32_bf16(bfr[     ks], afB[ks], a21aB, 0, 0, 0);
            a21bA = __builtin_amdgcn_mfma_f32_16x16x32_bf16(bfr[ 4 + ks], afA[ks], a21bA, 0, 0, 0);
            a21bB = __builtin_amdgcn_mfma_f32_16x16x32_bf16(bfr[ 4 + ks], afB[ks], a21bB, 0, 0, 0);
            a22aA = __builtin_amdgcn_mfma_f32_16x16x32_bf16(bfr[ 8 + ks], afA[ks], a22aA, 0, 0, 0);
            a22aB = __builtin_amdgcn_mfma_f32_16x16x32_bf16(bfr[ 8 + ks], afB[ks], a22aB, 0, 0, 0);
            a22bA = __builtin_amdgcn_mfma_f32_16x16x32_bf16(bfr[12 + ks], afA[ks], a22bA, 0, 0, 0);
            a22bB = __builtin_amdgcn_mfma_f32_16x16x32_bf16(bfr[12 + ks], afB[ks], a22bB, 0, 0, 0);
        }

        // heads: relu+pack into sigma-ordered B-fragments, 2 MFMA per chain
        uint4 h1A, h2A, h1B, h2B;
        h1A.x = pk_bf16(fmaxf(a21aA[0], 0.f), fmaxf(a21aA[1], 0.f));
        h1A.y = pk_bf16(fmaxf(a21aA[2], 0.f), fmaxf(a21aA[3], 0.f));
        h1A.z = pk_bf16(fmaxf(a21bA[0], 0.f), fmaxf(a21bA[1], 0.f));
        h1A.w = pk_bf16(fmaxf(a21bA[2], 0.f), fmaxf(a21bA[3], 0.f));
        h2A.x = pk_bf16(fmaxf(a22aA[0], 0.f), fmaxf(a22aA[1], 0.f));
        h2A.y = pk_bf16(fmaxf(a22aA[2], 0.f), fmaxf(a22aA[3], 0.f));
        h2A.z = pk_bf16(fmaxf(a22bA[0], 0.f), fmaxf(a22bA[1], 0.f));
        h2A.w = pk_bf16(fmaxf(a22bA[2], 0.f), fmaxf(a22bA[3], 0.f));
        h1B.x = pk_bf16(fmaxf(a21aB[0], 0.f), fmaxf(a21aB[1], 0.f));
        h1B.y = pk_bf16(fmaxf(a21aB[2], 0.f), fmaxf(a21aB[3], 0.f));
        h1B.z = pk_bf16(fmaxf(a21bB[0], 0.f), fmaxf(a21bB[1], 0.f));
        h1B.w = pk_bf16(fmaxf(a21bB[2], 0.f), fmaxf(a21bB[3], 0.f));
        h2B.x = pk_bf16(fmaxf(a22aB[0], 0.f), fmaxf(a22aB[1], 0.f));
        h2B.y = pk_bf16(fmaxf(a22aB[2], 0.f), fmaxf(a22aB[3], 0.f));
        h2B.z = pk_bf16(fmaxf(a22bB[0], 0.f), fmaxf(a22bB[1], 0.f));
        h2B.w = pk_bf16(fmaxf(a22bB[2], 0.f), fmaxf(a22bB[3], 0.f));

        f32x4 ini = {hb0, hb1, hb2, hb3};
        hdA = __builtin_amdgcn_mfma_f32_16x16x32_bf16(hA0, as_s8(h1A), ini, 0, 0, 0);
        hdA = __builtin_amdgcn_mfma_f32_16x16x32_bf16(hA1, as_s8(h2A), hdA, 0, 0, 0);
        hdB = __builtin_amdgcn_mfma_f32_16x16x32_bf16(hA0, as_s8(h1B), ini, 0, 0, 0);
        hdB = __builtin_amdgcn_mfma_f32_16x16x32_bf16(hA1, as_s8(h2B), hdB, 0, 0, 0);
    };

    auto LOADX = [&](int p, float xA[5], float xB[5]) {
        int rA = p * 32 + r15;      if (rA >= nB) rA = nB - 1;
        int rB = p * 32 + 16 + r15; if (rB >= nB) rB = nB - 1;
        const float* pA = x + (size_t)rA * 5;
        const float* pB = x + (size_t)rB * 5;
        #pragma unroll
        for (int c = 0; c < 5; ++c) { xA[c] = pA[c]; xB[c] = pB[c]; }
    };

    // ---- pipelined loop: LOADX(next) -> EPI(cur) -> MLP(next) ----
    int p = wid;
    float xrA[5], xrB[5];
    LOADX(p, xrA, xrB);
    f32x4 hdA, hdB;
    MLP(xrA, xrB, hdA, hdB);

    while (true) {
        const int nxt = p + nwaves;
        const bool has = nxt < npairs;
        float xnA[5], xnB[5];
        if (has) LOADX(nxt, xnA, xnB);   // issue loads early

        // ---- epilogue(cur): independent of xn; covers the load latency ----
        {
            float hs0 = __shfl(hdB[0], r15);
            float hs1 = __shfl(hdB[1], r15);
            float hs2 = __shfl(hdB[2], r15);
            float hs3 = __shfl(hdB[3], r15);
            if (lane < 32) {
                const bool sa = (lane < 16);
                float x31_0 = sa ? hdA[0] : hs0;
                float x31_1 = sa ? hdA[1] : hs1;
                float t32_0 = sa ? hdA[2] : hs2;
                float t32_1 = sa ? hdA[3] : hs3;

                float s0v = __fdividef(4.f, 1.f + __expf(-t32_0));
                float s1v = __fdividef(4.f, 1.f + __expf(-t32_1));
                float hcoef = s0v * s1v;

                float xo[5];
                #pragma unroll
                for (int c = 0; c < 5; ++c) {
                    float m = meanp[c], s = stdp[c];
                    float xc = sa ? xrA[c] : xrB[c];
                    float x0 = fmaf(xc, s, m);
                    xo[c] = fmaf(x0, s, m);
                }
                float px = xo[0], py = xo[1], th = xo[2], oppx = xo[3], oppy = xo[4];
                float st, ct;
                __sincosf(th, &st, &ct);

                float upper = INFINITY, lower = -INFINITY;
                #pragma unroll
                for (int j = 0; j < 9; ++j) {
                    float ox, oy, rr2;
                    if (j < 8) {
                        ox = obstacles[j * 3];
                        oy = obstacles[j * 3 + 1];
                        float rr = obstacles[j * 3 + 2];
                        rr2 = rr * rr;
                    } else {
                        ox = oppx; oy = oppy; rr2 = 0.3f * 0.3f;
                    }
                    float dx = px - ox, dy = py - oy;
                    float bar = fmaf(dx, dx, fmaf(dy, dy, -rr2));
                    float g1  = -2.f * fmaf(dx, ct, dy * st);
                    float ratio = __fdividef(hcoef * bar, (g1 != 0.f) ? g1 : 1.f);
                    if (g1 > 0.f) upper = fminf(upper, ratio);
                    if (g1 < 0.f) lower = fmaxf(lower, ratio);
                }
                float u1 = fminf(fmaxf(-x31_0, lower), upper);
                float u2 = -x31_1;

                int row = p * 32 + lane;
                if (row < nB) {
                    float2 o; o.x = u1; o.y = u2;
                    *reinterpret_cast<float2*>(out + 2 * (size_t)row) = o;
                }
            }
        }

        if (!has) break;
        MLP(xnA, xnB, hdA, hdB);         // loads are ready by now
        p = nxt;
        #pragma unroll
        for (int c = 0; c < 5; ++c) { xrA[c] = xnA[c]; xrB[c] = xnB[c]; }
    }
}

extern "C" void kernel_launch(void* const* d_in, const int* in_sizes, int n_in,
                              void* d_out, int out_size, void* d_ws, size_t ws_size,
                              hipStream_t stream) {
    const float* x         = (const float*)d_in[0];
    const float* meanp     = (const float*)d_in[1];
    const float* stdp      = (const float*)d_in[2];
    const float* W1        = (const float*)d_in[3];
    const float* b1        = (const float*)d_in[4];
    const float* W21       = (const float*)d_in[5];
    const float* b21       = (const float*)d_in[6];
    const float* W22       = (const float*)d_in[7];
    const float* b22       = (const float*)d_in[8];
    const float* W31       = (const float*)d_in[9];
    const float* b31       = (const float*)d_in[10];
    const float* W32       = (const float*)d_in[11];
    const float* b32       = (const float*)d_in[12];
    const float* obstacles = (const float*)d_in[13];
    float* out = (float*)d_out;

    int nB = in_sizes[0] / 5;
    bnet<<<GRID, BLOCK, 0, stream>>>(
        x, meanp, stdp, W1, b1, W21, b21, W22, b22,
        W31, b31, W32, b32, obstacles, out, nB);
}

// Round 14
// 19.469 us; speedup vs baseline: 1.0800x; 1.0800x over previous
//
#include <hip/hip_runtime.h>
#include <math.h>

typedef __attribute__((ext_vector_type(8))) short short8v;
typedef __attribute__((ext_vector_type(4))) float f32x4;

#define BLOCK 256
#define GRID  512

__device__ inline unsigned int pk_bf16(float lo, float hi) {
    unsigned int r;
    asm("v_cvt_pk_bf16_f32 %0, %1, %2" : "=v"(r) : "v"(lo), "v"(hi));
    return r;
}
__device__ inline short8v as_s8(uint4 v) { union { uint4 u; short8v s; } c; c.u = v; return c.s; }
__device__ inline f32x4 as_f4(float4 v) { union { float4 u; f32x4 s; } c; c.u = v; return c.s; }

__global__ __launch_bounds__(BLOCK, 2) void bnet(
    const float* __restrict__ x,
    const float* __restrict__ meanp, const float* __restrict__ stdp,
    const float* __restrict__ W1,  const float* __restrict__ b1,
    const float* __restrict__ W21, const float* __restrict__ b21,
    const float* __restrict__ W22, const float* __restrict__ b22,
    const float* __restrict__ W31, const float* __restrict__ b31,
    const float* __restrict__ W32, const float* __restrict__ b32,
    const float* __restrict__ obstacles,
    float* __restrict__ out, int nB)
{
    // Layer-1 A-frags: [g*64+lane]; lanes<16 hold W1 row 16g+m (k=0..4 w, k=5 b1).
    __shared__ uint4 w1frag[8 * 64];                  // 8 KB
    // Layer-2 A-frags with pi-permuted K (verified rounds 4..13).
    __shared__ uint4 fragB[16 * 64];                  // 16 KB
    // Head A-frags (verified round 6/9/12): sigma-permuted W31/W32 rows.
    __shared__ uint4 headA[2 * 64];                   // 2 KB
    __shared__ float b2s[64];                         // b21[32] | b22[32]

    const int t = threadIdx.x;

    {   // zero w1frag (lanes >=16 must be zero)
        uint4 z = {0u, 0u, 0u, 0u};
        w1frag[t] = z; w1frag[t + 256] = z;
    }
    __syncthreads();
    if (t < 128) {   // W1 fragments
        int m = t & 15, g = t >> 4;
        int u = 16 * g + m;
        const float* wr = W1 + u * 5;
        uint4 v;
        v.x = pk_bf16(wr[0], wr[1]);
        v.y = pk_bf16(wr[2], wr[3]);
        v.z = pk_bf16(wr[4], b1[u]);
        v.w = 0u;
        w1frag[g * 64 + m] = v;
    } else {         // head A-fragments (threads 128..255) - round 6 verified
        int e  = t - 128;
        int ks = e >> 6, l = e & 63, m = l & 15, qq = l >> 4;
        float v[8];
        #pragma unroll
        for (int j = 0; j < 8; ++j) {
            int u = 16 * ((j >> 2) & 1) + 4 * qq + (j & 3);   // sigma^-1
            float val = 0.f;
            if (m == 0 && ks == 0) val = W31[u];
            if (m == 1 && ks == 0) val = W31[32 + u];
            if (m == 2 && ks == 1) val = W32[u];
            if (m == 3 && ks == 1) val = W32[32 + u];
            v[j] = val;
        }
        uint4 h;
        h.x = pk_bf16(v[0], v[1]); h.y = pk_bf16(v[2], v[3]);
        h.z = pk_bf16(v[4], v[5]); h.w = pk_bf16(v[6], v[7]);
        headA[ks * 64 + l] = h;
    }
    if (t < 64) b2s[t] = (t < 32) ? b21[t] : b22[t - 32];
    {   // layer-2 fragments (verified mapping)
        const float4* w21v = (const float4*)W21;
        const float4* w22v = (const float4*)W22;
        #pragma unroll
        for (int e = 0; e < 4; ++e) {
            int g4   = t + e * 256;
            int uo   = g4 >> 5;
            int h0   = (g4 & 31) << 2;
            int ks   = h0 >> 5;
            int jh   = (h0 >> 4) & 1;
            int qq   = (h0 >> 2) & 3;
            int ln   = (qq << 4) | (uo & 15);
            int half = uo >> 4;
            float4 f1 = w21v[g4];
            float4 f2 = w22v[g4];
            unsigned int* dA = (unsigned int*)&fragB[(half * 4 + ks) * 64 + ln];
            unsigned int* dB = (unsigned int*)&fragB[(8 + half * 4 + ks) * 64 + ln];
            dA[jh * 2] = pk_bf16(f1.x, f1.y); dA[jh * 2 + 1] = pk_bf16(f1.z, f1.w);
            dB[jh * 2] = pk_bf16(f2.x, f2.y); dB[jh * 2 + 1] = pk_bf16(f2.z, f2.w);
        }
    }
    __syncthreads();

    const int lane = t & 63;
    const int q    = lane >> 4;
    const int r15  = lane & 15;
    const int wid    = blockIdx.x * 4 + (t >> 6);
    const int nwaves = GRID * 4;
    const int npairs = (nB + 31) >> 5;
    if (wid >= npairs) return;

    // Resident: W2 fragments (64 VGPR) + head A-frags (8 VGPR).
    short8v bfr[16];
    #pragma unroll
    for (int i = 0; i < 16; ++i) bfr[i] = as_s8(fragB[i * 64 + lane]);
    const short8v hfr0 = as_s8(headA[lane]);
    const short8v hfr1 = as_s8(headA[64 + lane]);
    const float4* b2v = (const float4*)b2s;

    const float hb0 = b31[0], hb1 = b31[1], hb2 = b32[0], hb3 = b32[1];

    auto LOADX = [&](int p, float xA[5], float xB[5]) {
        int rA = p * 32 + r15;      if (rA >= nB) rA = nB - 1;
        int rB = p * 32 + 16 + r15; if (rB >= nB) rB = nB - 1;
        const float* pA = x + (size_t)rA * 5;
        const float* pB = x + (size_t)rB * 5;
        #pragma unroll
        for (int c = 0; c < 5; ++c) { xA[c] = pA[c]; xB[c] = pB[c]; }
    };

    // MLP for TWO 32-row pairs (4 independent 16-row chains), L1->pack->L2
    // fused per-ks so af is transient. 2x the independent work per phase
    // fills dependency-latency bubbles (the R7/R9 lever, deepened).
    auto MLP4 = [&](const float xA0[5], const float xB0[5],
                    const float xA1[5], const float xB1[5],
                    f32x4& hd0A, f32x4& hd0B, f32x4& hd1A, f32x4& hd1B) {
        uint4 t0a, t0b, t1a, t1b;
        t0a.x = pk_bf16(xA0[0], xA0[1]); t0a.y = pk_bf16(xA0[2], xA0[3]);
        t0a.z = pk_bf16(xA0[4], 1.0f);   t0a.w = 0u;
        t0b.x = pk_bf16(xB0[0], xB0[1]); t0b.y = pk_bf16(xB0[2], xB0[3]);
        t0b.z = pk_bf16(xB0[4], 1.0f);   t0b.w = 0u;
        t1a.x = pk_bf16(xA1[0], xA1[1]); t1a.y = pk_bf16(xA1[2], xA1[3]);
        t1a.z = pk_bf16(xA1[4], 1.0f);   t1a.w = 0u;
        t1b.x = pk_bf16(xB1[0], xB1[1]); t1b.y = pk_bf16(xB1[2], xB1[3]);
        t1b.z = pk_bf16(xB1[4], 1.0f);   t1b.w = 0u;
        short8v xf0A = as_s8(t0a), xf0B = as_s8(t0b);
        short8v xf1A = as_s8(t1a), xf1B = as_s8(t1b);

        f32x4 i0 = as_f4(b2v[q]),     i1 = as_f4(b2v[4 + q]);
        f32x4 i2 = as_f4(b2v[8 + q]), i3 = as_f4(b2v[12 + q]);
        f32x4 A0_21a = i0, A0_21b = i1, A0_22a = i2, A0_22b = i3;
        f32x4 B0_21a = i0, B0_21b = i1, B0_22a = i2, B0_22b = i3;
        f32x4 A1_21a = i0, A1_21b = i1, A1_22a = i2, A1_22b = i3;
        f32x4 B1_21a = i0, B1_21b = i1, B1_22a = i2, B1_22b = i3;

        #pragma unroll
        for (int ks = 0; ks < 4; ++ks) {
            f32x4 z = {0.f, 0.f, 0.f, 0.f};
            short8v w0  = as_s8(w1frag[(2 * ks) * 64 + lane]);
            short8v w1v = as_s8(w1frag[(2 * ks + 1) * 64 + lane]);
            // layer 1: 8 MFMAs, 4 independent chains
            f32x4 u0A = __builtin_amdgcn_mfma_f32_16x16x32_bf16(w0,  xf0A, z, 0, 0, 0);
            f32x4 v0A = __builtin_amdgcn_mfma_f32_16x16x32_bf16(w1v, xf0A, z, 0, 0, 0);
            f32x4 u0B = __builtin_amdgcn_mfma_f32_16x16x32_bf16(w0,  xf0B, z, 0, 0, 0);
            f32x4 v0B = __builtin_amdgcn_mfma_f32_16x16x32_bf16(w1v, xf0B, z, 0, 0, 0);
            f32x4 u1A = __builtin_amdgcn_mfma_f32_16x16x32_bf16(w0,  xf1A, z, 0, 0, 0);
            f32x4 v1A = __builtin_amdgcn_mfma_f32_16x16x32_bf16(w1v, xf1A, z, 0, 0, 0);
            f32x4 u1B = __builtin_amdgcn_mfma_f32_16x16x32_bf16(w0,  xf1B, z, 0, 0, 0);
            f32x4 v1B = __builtin_amdgcn_mfma_f32_16x16x32_bf16(w1v, xf1B, z, 0, 0, 0);
            // relu + pack (same order as verified R12)
            uint4 pa, pb, pc, pd;
            pa.x = pk_bf16(fmaxf(u0A[0], 0.f), fmaxf(u0A[1], 0.f));
            pa.y = pk_bf16(fmaxf(u0A[2], 0.f), fmaxf(u0A[3], 0.f));
            pa.z = pk_bf16(fmaxf(v0A[0], 0.f), fmaxf(v0A[1], 0.f));
            pa.w = pk_bf16(fmaxf(v0A[2], 0.f), fmaxf(v0A[3], 0.f));
            pb.x = pk_bf16(fmaxf(u0B[0], 0.f), fmaxf(u0B[1], 0.f));
            pb.y = pk_bf16(fmaxf(u0B[2], 0.f), fmaxf(u0B[3], 0.f));
            pb.z = pk_bf16(fmaxf(v0B[0], 0.f), fmaxf(v0B[1], 0.f));
            pb.w = pk_bf16(fmaxf(v0B[2], 0.f), fmaxf(v0B[3], 0.f));
            pc.x = pk_bf16(fmaxf(u1A[0], 0.f), fmaxf(u1A[1], 0.f));
            pc.y = pk_bf16(fmaxf(u1A[2], 0.f), fmaxf(u1A[3], 0.f));
            pc.z = pk_bf16(fmaxf(v1A[0], 0.f), fmaxf(v1A[1], 0.f));
            pc.w = pk_bf16(fmaxf(v1A[2], 0.f), fmaxf(v1A[3], 0.f));
            pd.x = pk_bf16(fmaxf(u1B[0], 0.f), fmaxf(u1B[1], 0.f));
            pd.y = pk_bf16(fmaxf(u1B[2], 0.f), fmaxf(u1B[3], 0.f));
            pd.z = pk_bf16(fmaxf(v1B[0], 0.f), fmaxf(v1B[1], 0.f));
            pd.w = pk_bf16(fmaxf(v1B[2], 0.f), fmaxf(v1B[3], 0.f));
            short8v af0A = as_s8(pa), af0B = as_s8(pb);
            short8v af1A = as_s8(pc), af1B = as_s8(pd);
            // layer 2: 16 MFMAs, af transient
            A0_21a = __builtin_amdgcn_mfma_f32_16x16x32_bf16(bfr[     ks], af0A, A0_21a, 0, 0, 0);
            B0_21a = __builtin_amdgcn_mfma_f32_16x16x32_bf16(bfr[     ks], af0B, B0_21a, 0, 0, 0);
            A1_21a = __builtin_amdgcn_mfma_f32_16x16x32_bf16(bfr[     ks], af1A, A1_21a, 0, 0, 0);
            B1_21a = __builtin_amdgcn_mfma_f32_16x16x32_bf16(bfr[     ks], af1B, B1_21a, 0, 0, 0);
            A0_21b = __builtin_amdgcn_mfma_f32_16x16x32_bf16(bfr[ 4 + ks], af0A, A0_21b, 0, 0, 0);
            B0_21b = __builtin_amdgcn_mfma_f32_16x16x32_bf16(bfr[ 4 + ks], af0B, B0_21b, 0, 0, 0);
            A1_21b = __builtin_amdgcn_mfma_f32_16x16x32_bf16(bfr[ 4 + ks], af1A, A1_21b, 0, 0, 0);
            B1_21b = __builtin_amdgcn_mfma_f32_16x16x32_bf16(bfr[ 4 + ks], af1B, B1_21b, 0, 0, 0);
            A0_22a = __builtin_amdgcn_mfma_f32_16x16x32_bf16(bfr[ 8 + ks], af0A, A0_22a, 0, 0, 0);
            B0_22a = __builtin_amdgcn_mfma_f32_16x16x32_bf16(bfr[ 8 + ks], af0B, B0_22a, 0, 0, 0);
            A1_22a = __builtin_amdgcn_mfma_f32_16x16x32_bf16(bfr[ 8 + ks], af1A, A1_22a, 0, 0, 0);
            B1_22a = __builtin_amdgcn_mfma_f32_16x16x32_bf16(bfr[ 8 + ks], af1B, B1_22a, 0, 0, 0);
            A0_22b = __builtin_amdgcn_mfma_f32_16x16x32_bf16(bfr[12 + ks], af0A, A0_22b, 0, 0, 0);
            B0_22b = __builtin_amdgcn_mfma_f32_16x16x32_bf16(bfr[12 + ks], af0B, B0_22b, 0, 0, 0);
            A1_22b = __builtin_amdgcn_mfma_f32_16x16x32_bf16(bfr[12 + ks], af1A, A1_22b, 0, 0, 0);
            B1_22b = __builtin_amdgcn_mfma_f32_16x16x32_bf16(bfr[12 + ks], af1B, B1_22b, 0, 0, 0);
        }

        // heads: relu+pack into sigma-ordered B-fragments, 2 MFMA per chain
        f32x4 ini = {hb0, hb1, hb2, hb3};
        {
            uint4 h1, h2;
            h1.x = pk_bf16(fmaxf(A0_21a[0], 0.f), fmaxf(A0_21a[1], 0.f));
            h1.y = pk_bf16(fmaxf(A0_21a[2], 0.f), fmaxf(A0_21a[3], 0.f));
            h1.z = pk_bf16(fmaxf(A0_21b[0], 0.f), fmaxf(A0_21b[1], 0.f));
            h1.w = pk_bf16(fmaxf(A0_21b[2], 0.f), fmaxf(A0_21b[3], 0.f));
            h2.x = pk_bf16(fmaxf(A0_22a[0], 0.f), fmaxf(A0_22a[1], 0.f));
            h2.y = pk_bf16(fmaxf(A0_22a[2], 0.f), fmaxf(A0_22a[3], 0.f));
            h2.z = pk_bf16(fmaxf(A0_22b[0], 0.f), fmaxf(A0_22b[1], 0.f));
            h2.w = pk_bf16(fmaxf(A0_22b[2], 0.f), fmaxf(A0_22b[3], 0.f));
            hd0A = __builtin_amdgcn_mfma_f32_16x16x32_bf16(hfr0, as_s8(h1), ini, 0, 0, 0);
            hd0A = __builtin_amdgcn_mfma_f32_16x16x32_bf16(hfr1, as_s8(h2), hd0A, 0, 0, 0);
        }
        {
            uint4 h1, h2;
            h1.x = pk_bf16(fmaxf(B0_21a[0], 0.f), fmaxf(B0_21a[1], 0.f));
            h1.y = pk_bf16(fmaxf(B0_21a[2], 0.f), fmaxf(B0_21a[3], 0.f));
            h1.z = pk_bf16(fmaxf(B0_21b[0], 0.f), fmaxf(B0_21b[1], 0.f));
            h1.w = pk_bf16(fmaxf(B0_21b[2], 0.f), fmaxf(B0_21b[3], 0.f));
            h2.x = pk_bf16(fmaxf(B0_22a[0], 0.f), fmaxf(B0_22a[1], 0.f));
            h2.y = pk_bf16(fmaxf(B0_22a[2], 0.f), fmaxf(B0_22a[3], 0.f));
            h2.z = pk_bf16(fmaxf(B0_22b[0], 0.f), fmaxf(B0_22b[1], 0.f));
            h2.w = pk_bf16(fmaxf(B0_22b[2], 0.f), fmaxf(B0_22b[3], 0.f));
            hd0B = __builtin_amdgcn_mfma_f32_16x16x32_bf16(hfr0, as_s8(h1), ini, 0, 0, 0);
            hd0B = __builtin_amdgcn_mfma_f32_16x16x32_bf16(hfr1, as_s8(h2), hd0B, 0, 0, 0);
        }
        {
            uint4 h1, h2;
            h1.x = pk_bf16(fmaxf(A1_21a[0], 0.f), fmaxf(A1_21a[1], 0.f));
            h1.y = pk_bf16(fmaxf(A1_21a[2], 0.f), fmaxf(A1_21a[3], 0.f));
            h1.z = pk_bf16(fmaxf(A1_21b[0], 0.f), fmaxf(A1_21b[1], 0.f));
            h1.w = pk_bf16(fmaxf(A1_21b[2], 0.f), fmaxf(A1_21b[3], 0.f));
            h2.x = pk_bf16(fmaxf(A1_22a[0], 0.f), fmaxf(A1_22a[1], 0.f));
            h2.y = pk_bf16(fmaxf(A1_22a[2], 0.f), fmaxf(A1_22a[3], 0.f));
            h2.z = pk_bf16(fmaxf(A1_22b[0], 0.f), fmaxf(A1_22b[1], 0.f));
            h2.w = pk_bf16(fmaxf(A1_22b[2], 0.f), fmaxf(A1_22b[3], 0.f));
            hd1A = __builtin_amdgcn_mfma_f32_16x16x32_bf16(hfr0, as_s8(h1), ini, 0, 0, 0);
            hd1A = __builtin_amdgcn_mfma_f32_16x16x32_bf16(hfr1, as_s8(h2), hd1A, 0, 0, 0);
        }
        {
            uint4 h1, h2;
            h1.x = pk_bf16(fmaxf(B1_21a[0], 0.f), fmaxf(B1_21a[1], 0.f));
            h1.y = pk_bf16(fmaxf(B1_21a[2], 0.f), fmaxf(B1_21a[3], 0.f));
            h1.z = pk_bf16(fmaxf(B1_21b[0], 0.f), fmaxf(B1_21b[1], 0.f));
            h1.w = pk_bf16(fmaxf(B1_21b[2], 0.f), fmaxf(B1_21b[3], 0.f));
            h2.x = pk_bf16(fmaxf(B1_22a[0], 0.f), fmaxf(B1_22a[1], 0.f));
            h2.y = pk_bf16(fmaxf(B1_22a[2], 0.f), fmaxf(B1_22a[3], 0.f));
            h2.z = pk_bf16(fmaxf(B1_22b[0], 0.f), fmaxf(B1_22b[1], 0.f));
            h2.w = pk_bf16(fmaxf(B1_22b[2], 0.f), fmaxf(B1_22b[3], 0.f));
            hd1B = __builtin_amdgcn_mfma_f32_16x16x32_bf16(hfr0, as_s8(h1), ini, 0, 0, 0);
            hd1B = __builtin_amdgcn_mfma_f32_16x16x32_bf16(hfr1, as_s8(h2), hd1B, 0, 0, 0);
        }
    };

    auto EPI = [&](int p, const float xA[5], const float xB[5],
                   const f32x4& hdA, const f32x4& hdB) {
        float hs0 = __shfl(hdB[0], r15);
        float hs1 = __shfl(hdB[1], r15);
        float hs2 = __shfl(hdB[2], r15);
        float hs3 = __shfl(hdB[3], r15);
        if (lane < 32) {
            const bool sa = (lane < 16);
            float x31_0 = sa ? hdA[0] : hs0;
            float x31_1 = sa ? hdA[1] : hs1;
            float t32_0 = sa ? hdA[2] : hs2;
            float t32_1 = sa ? hdA[3] : hs3;

            float s0v = __fdividef(4.f, 1.f + __expf(-t32_0));
            float s1v = __fdividef(4.f, 1.f + __expf(-t32_1));
            float hcoef = s0v * s1v;

            float xo[5];
            #pragma unroll
            for (int c = 0; c < 5; ++c) {
                float m = meanp[c], s = stdp[c];
                float xc = sa ? xA[c] : xB[c];
                float x0 = fmaf(xc, s, m);
                xo[c] = fmaf(x0, s, m);
            }
            float px = xo[0], py = xo[1], th = xo[2], oppx = xo[3], oppy = xo[4];
            float st, ct;
            __sincosf(th, &st, &ct);

            float upper = INFINITY, lower = -INFINITY;
            #pragma unroll
            for (int j = 0; j < 9; ++j) {
                float ox, oy, rr2;
                if (j < 8) {
                    ox = obstacles[j * 3];
                    oy = obstacles[j * 3 + 1];
                    float rr = obstacles[j * 3 + 2];
                    rr2 = rr * rr;
                } else {
                    ox = oppx; oy = oppy; rr2 = 0.3f * 0.3f;
                }
                float dx = px - ox, dy = py - oy;
                float bar = fmaf(dx, dx, fmaf(dy, dy, -rr2));
                float g1  = -2.f * fmaf(dx, ct, dy * st);
                float ratio = __fdividef(hcoef * bar, (g1 != 0.f) ? g1 : 1.f);
                if (g1 > 0.f) upper = fminf(upper, ratio);
                if (g1 < 0.f) lower = fmaxf(lower, ratio);
            }
            float u1 = fminf(fmaxf(-x31_0, lower), upper);
            float u2 = -x31_1;

            int row = p * 32 + lane;
            if (row < nB) {
                float2 o; o.x = u1; o.y = u2;
                *reinterpret_cast<float2*>(out + 2 * (size_t)row) = o;
            }
        }
    };

    // ---- straight-line 4 pairs: MLP4(0,1) -> EPI(0) -> MLP4(2,3) -> EPI(1..3)
    // EPI(0)/EPI(1) interleave with the second MLP4's MFMAs in the scheduler.
    const int P0 = wid;
    const int P1 = wid + nwaves;
    const int P2 = wid + 2 * nwaves;
    const int P3 = wid + 3 * nwaves;

    float x0A[5], x0B[5], x1A[5], x1B[5], x2A[5], x2B[5], x3A[5], x3B[5];
    LOADX(P0, x0A, x0B);
    LOADX(P1, x1A, x1B);
    f32x4 hd0A, hd0B, hd1A, hd1B, hd2A, hd2B, hd3A, hd3B;
    MLP4(x0A, x0B, x1A, x1B, hd0A, hd0B, hd1A, hd1B);
    LOADX(P2, x2A, x2B);
    LOADX(P3, x3A, x3B);
    EPI(P0, x0A, x0B, hd0A, hd0B);
    MLP4(x2A, x2B, x3A, x3B, hd2A, hd2B, hd3A, hd3B);
    EPI(P1, x1A, x1B, hd1A, hd1B);
    EPI(P2, x2A, x2B, hd2A, hd2B);
    EPI(P3, x3A, x3B, hd3A, hd3B);
}

extern "C" void kernel_launch(void* const* d_in, const int* in_sizes, int n_in,
                              void* d_out, int out_size, void* d_ws, size_t ws_size,
                              hipStream_t stream) {
    const float* x         = (const float*)d_in[0];
    const float* meanp     = (const float*)d_in[1];
    const float* stdp      = (const float*)d_in[2];
    const float* W1        = (const float*)d_in[3];
    const float* b1        = (const float*)d_in[4];
    const float* W21       = (const float*)d_in[5];
    const float* b21       = (const float*)d_in[6];
    const float* W22       = (const float*)d_in[7];
    const float* b22       = (const float*)d_in[8];
    const float* W31       = (const float*)d_in[9];
    const float* b31       = (const float*)d_in[10];
    const float* W32       = (const float*)d_in[11];
    const float* b32       = (const float*)d_in[12];
    const float* obstacles = (const float*)d_in[13];
    float* out = (float*)d_out;

    int nB = in_sizes[0] / 5;
    bnet<<<GRID, BLOCK, 0, stream>>>(
        x, meanp, stdp, W1, b1, W21, b21, W22, b22,
        W31, b31, W32, b32, obstacles, out, nB);
}

// Round 17
// 18.916 us; speedup vs baseline: 1.1116x; 1.0292x over previous
//
#include <hip/hip_runtime.h>
#include <math.h>

typedef __attribute__((ext_vector_type(8))) short short8v;
typedef __attribute__((ext_vector_type(4))) float f32x4;

#define BLOCK 256
#define GRID  512

__device__ inline unsigned int pk_bf16(float lo, float hi) {
    unsigned int r;
    asm("v_cvt_pk_bf16_f32 %0, %1, %2" : "=v"(r) : "v"(lo), "v"(hi));
    return r;
}
__device__ inline short8v as_s8(uint4 v) { union { uint4 u; short8v s; } c; c.u = v; return c.s; }
__device__ inline f32x4 as_f4(float4 v) { union { float4 u; f32x4 s; } c; c.u = v; return c.s; }

__global__ __launch_bounds__(BLOCK, 2) void bnet(
    const float* __restrict__ x,
    const float* __restrict__ meanp, const float* __restrict__ stdp,
    const float* __restrict__ W1,  const float* __restrict__ b1,
    const float* __restrict__ W21, const float* __restrict__ b21,
    const float* __restrict__ W22, const float* __restrict__ b22,
    const float* __restrict__ W31, const float* __restrict__ b31,
    const float* __restrict__ W32, const float* __restrict__ b32,
    const float* __restrict__ obstacles,
    float* __restrict__ out, int nB)
{
    // Layer-1 A-frags: [g*64+lane]; lanes<16 hold W1 row 16g+m (k=0..4 w, k=5 b1).
    __shared__ uint4 w1frag[8 * 64];                  // 8 KB
    // Layer-2 A-frags with pi-permuted K (verified rounds 4..14).
    __shared__ uint4 fragB[16 * 64];                  // 16 KB
    // Head A-frags (verified round 6/9/12): sigma-permuted W31/W32 rows.
    __shared__ uint4 headA[2 * 64];                   // 2 KB
    __shared__ float b2s[64];                         // b21[32] | b22[32]

    const int t = threadIdx.x;

    {   // zero w1frag (lanes >=16 must be zero)
        uint4 z = {0u, 0u, 0u, 0u};
        w1frag[t] = z; w1frag[t + 256] = z;
    }
    __syncthreads();
    if (t < 128) {   // W1 fragments
        int m = t & 15, g = t >> 4;
        int u = 16 * g + m;
        const float* wr = W1 + u * 5;
        uint4 v;
        v.x = pk_bf16(wr[0], wr[1]);
        v.y = pk_bf16(wr[2], wr[3]);
        v.z = pk_bf16(wr[4], b1[u]);
        v.w = 0u;
        w1frag[g * 64 + m] = v;
    } else {         // head A-fragments (threads 128..255) - round 6 verified
        int e  = t - 128;
        int ks = e >> 6, l = e & 63, m = l & 15, qq = l >> 4;
        float v[8];
        #pragma unroll
        for (int j = 0; j < 8; ++j) {
            int u = 16 * ((j >> 2) & 1) + 4 * qq + (j & 3);   // sigma^-1
            float val = 0.f;
            if (m == 0 && ks == 0) val = W31[u];
            if (m == 1 && ks == 0) val = W31[32 + u];
            if (m == 2 && ks == 1) val = W32[u];
            if (m == 3 && ks == 1) val = W32[32 + u];
            v[j] = val;
        }
        uint4 h;
        h.x = pk_bf16(v[0], v[1]); h.y = pk_bf16(v[2], v[3]);
        h.z = pk_bf16(v[4], v[5]); h.w = pk_bf16(v[6], v[7]);
        headA[ks * 64 + l] = h;
    }
    if (t < 64) b2s[t] = (t < 32) ? b21[t] : b22[t - 32];
    {   // layer-2 fragments (verified mapping)
        const float4* w21v = (const float4*)W21;
        const float4* w22v = (const float4*)W22;
        #pragma unroll
        for (int e = 0; e < 4; ++e) {
            int g4   = t + e * 256;
            int uo   = g4 >> 5;
            int h0   = (g4 & 31) << 2;
            int ks   = h0 >> 5;
            int jh   = (h0 >> 4) & 1;
            int qq   = (h0 >> 2) & 3;
            int ln   = (qq << 4) | (uo & 15);
            int half = uo >> 4;
            float4 f1 = w21v[g4];
            float4 f2 = w22v[g4];
            unsigned int* dA = (unsigned int*)&fragB[(half * 4 + ks) * 64 + ln];
            unsigned int* dB = (unsigned int*)&fragB[(8 + half * 4 + ks) * 64 + ln];
            dA[jh * 2] = pk_bf16(f1.x, f1.y); dA[jh * 2 + 1] = pk_bf16(f1.z, f1.w);
            dB[jh * 2] = pk_bf16(f2.x, f2.y); dB[jh * 2 + 1] = pk_bf16(f2.z, f2.w);
        }
    }
    __syncthreads();

    const int lane = t & 63;
    const int q    = lane >> 4;
    const int r15  = lane & 15;
    const int wid    = blockIdx.x * 4 + (t >> 6);
    const int nwaves = GRID * 4;
    const int npairs = (nB + 31) >> 5;
    if (wid >= npairs) return;

    // Resident: W2 fragments (64 VGPR) + head A-frags (8 VGPR).
    short8v bfr[16];
    #pragma unroll
    for (int i = 0; i < 16; ++i) bfr[i] = as_s8(fragB[i * 64 + lane]);
    const short8v hfr0 = as_s8(headA[lane]);
    const short8v hfr1 = as_s8(headA[64 + lane]);
    const float4* b2v = (const float4*)b2s;

    const float hb0 = b31[0], hb1 = b31[1], hb2 = b32[0], hb3 = b32[1];

    auto LOADX = [&](int p, float xA[5], float xB[5]) {
        int rA = p * 32 + r15;      if (rA >= nB) rA = nB - 1;
        int rB = p * 32 + 16 + r15; if (rB >= nB) rB = nB - 1;
        const float* pA = x + (size_t)rA * 5;
        const float* pB = x + (size_t)rB * 5;
        #pragma unroll
        for (int c = 0; c < 5; ++c) { xA[c] = pA[c]; xB[c] = pB[c]; }
    };

    // MLP for TWO 32-row pairs (4 independent 16-row chains), R14 verbatim,
    // wrapped in s_setprio(1)/(0): pure CU-scheduler hint (T5). Waves in the
    // MFMA-dense phase win issue arbitration over waves doing EPI VALU work.
    auto MLP4 = [&](const float xA0[5], const float xB0[5],
                    const float xA1[5], const float xB1[5],
                    f32x4& hd0A, f32x4& hd0B, f32x4& hd1A, f32x4& hd1B) {
        uint4 t0a, t0b, t1a, t1b;
        t0a.x = pk_bf16(xA0[0], xA0[1]); t0a.y = pk_bf16(xA0[2], xA0[3]);
        t0a.z = pk_bf16(xA0[4], 1.0f);   t0a.w = 0u;
        t0b.x = pk_bf16(xB0[0], xB0[1]); t0b.y = pk_bf16(xB0[2], xB0[3]);
        t0b.z = pk_bf16(xB0[4], 1.0f);   t0b.w = 0u;
        t1a.x = pk_bf16(xA1[0], xA1[1]); t1a.y = pk_bf16(xA1[2], xA1[3]);
        t1a.z = pk_bf16(xA1[4], 1.0f);   t1a.w = 0u;
        t1b.x = pk_bf16(xB1[0], xB1[1]); t1b.y = pk_bf16(xB1[2], xB1[3]);
        t1b.z = pk_bf16(xB1[4], 1.0f);   t1b.w = 0u;
        short8v xf0A = as_s8(t0a), xf0B = as_s8(t0b);
        short8v xf1A = as_s8(t1a), xf1B = as_s8(t1b);

        f32x4 i0 = as_f4(b2v[q]),     i1 = as_f4(b2v[4 + q]);
        f32x4 i2 = as_f4(b2v[8 + q]), i3 = as_f4(b2v[12 + q]);
        f32x4 A0_21a = i0, A0_21b = i1, A0_22a = i2, A0_22b = i3;
        f32x4 B0_21a = i0, B0_21b = i1, B0_22a = i2, B0_22b = i3;
        f32x4 A1_21a = i0, A1_21b = i1, A1_22a = i2, A1_22b = i3;
        f32x4 B1_21a = i0, B1_21b = i1, B1_22a = i2, B1_22b = i3;

        __builtin_amdgcn_s_setprio(1);
        #pragma unroll
        for (int ks = 0; ks < 4; ++ks) {
            f32x4 z = {0.f, 0.f, 0.f, 0.f};
            short8v w0  = as_s8(w1frag[(2 * ks) * 64 + lane]);
            short8v w1v = as_s8(w1frag[(2 * ks + 1) * 64 + lane]);
            // layer 1: 8 MFMAs, 4 independent chains
            f32x4 u0A = __builtin_amdgcn_mfma_f32_16x16x32_bf16(w0,  xf0A, z, 0, 0, 0);
            f32x4 v0A = __builtin_amdgcn_mfma_f32_16x16x32_bf16(w1v, xf0A, z, 0, 0, 0);
            f32x4 u0B = __builtin_amdgcn_mfma_f32_16x16x32_bf16(w0,  xf0B, z, 0, 0, 0);
            f32x4 v0B = __builtin_amdgcn_mfma_f32_16x16x32_bf16(w1v, xf0B, z, 0, 0, 0);
            f32x4 u1A = __builtin_amdgcn_mfma_f32_16x16x32_bf16(w0,  xf1A, z, 0, 0, 0);
            f32x4 v1A = __builtin_amdgcn_mfma_f32_16x16x32_bf16(w1v, xf1A, z, 0, 0, 0);
            f32x4 u1B = __builtin_amdgcn_mfma_f32_16x16x32_bf16(w0,  xf1B, z, 0, 0, 0);
            f32x4 v1B = __builtin_amdgcn_mfma_f32_16x16x32_bf16(w1v, xf1B, z, 0, 0, 0);
            // relu + pack (same order as verified R12/R14)
            uint4 pa, pb, pc, pd;
            pa.x = pk_bf16(fmaxf(u0A[0], 0.f), fmaxf(u0A[1], 0.f));
            pa.y = pk_bf16(fmaxf(u0A[2], 0.f), fmaxf(u0A[3], 0.f));
            pa.z = pk_bf16(fmaxf(v0A[0], 0.f), fmaxf(v0A[1], 0.f));
            pa.w = pk_bf16(fmaxf(v0A[2], 0.f), fmaxf(v0A[3], 0.f));
            pb.x = pk_bf16(fmaxf(u0B[0], 0.f), fmaxf(u0B[1], 0.f));
            pb.y = pk_bf16(fmaxf(u0B[2], 0.f), fmaxf(u0B[3], 0.f));
            pb.z = pk_bf16(fmaxf(v0B[0], 0.f), fmaxf(v0B[1], 0.f));
            pb.w = pk_bf16(fmaxf(v0B[2], 0.f), fmaxf(v0B[3], 0.f));
            pc.x = pk_bf16(fmaxf(u1A[0], 0.f), fmaxf(u1A[1], 0.f));
            pc.y = pk_bf16(fmaxf(u1A[2], 0.f), fmaxf(u1A[3], 0.f));
            pc.z = pk_bf16(fmaxf(v1A[0], 0.f), fmaxf(v1A[1], 0.f));
            pc.w = pk_bf16(fmaxf(v1A[2], 0.f), fmaxf(v1A[3], 0.f));
            pd.x = pk_bf16(fmaxf(u1B[0], 0.f), fmaxf(u1B[1], 0.f));
            pd.y = pk_bf16(fmaxf(u1B[2], 0.f), fmaxf(u1B[3], 0.f));
            pd.z = pk_bf16(fmaxf(v1B[0], 0.f), fmaxf(v1B[1], 0.f));
            pd.w = pk_bf16(fmaxf(v1B[2], 0.f), fmaxf(v1B[3], 0.f));
            short8v af0A = as_s8(pa), af0B = as_s8(pb);
            short8v af1A = as_s8(pc), af1B = as_s8(pd);
            // layer 2: 16 MFMAs, af transient
            A0_21a = __builtin_amdgcn_mfma_f32_16x16x32_bf16(bfr[     ks], af0A, A0_21a, 0, 0, 0);
            B0_21a = __builtin_amdgcn_mfma_f32_16x16x32_bf16(bfr[     ks], af0B, B0_21a, 0, 0, 0);
            A1_21a = __builtin_amdgcn_mfma_f32_16x16x32_bf16(bfr[     ks], af1A, A1_21a, 0, 0, 0);
            B1_21a = __builtin_amdgcn_mfma_f32_16x16x32_bf16(bfr[     ks], af1B, B1_21a, 0, 0, 0);
            A0_21b = __builtin_amdgcn_mfma_f32_16x16x32_bf16(bfr[ 4 + ks], af0A, A0_21b, 0, 0, 0);
            B0_21b = __builtin_amdgcn_mfma_f32_16x16x32_bf16(bfr[ 4 + ks], af0B, B0_21b, 0, 0, 0);
            A1_21b = __builtin_amdgcn_mfma_f32_16x16x32_bf16(bfr[ 4 + ks], af1A, A1_21b, 0, 0, 0);
            B1_21b = __builtin_amdgcn_mfma_f32_16x16x32_bf16(bfr[ 4 + ks], af1B, B1_21b, 0, 0, 0);
            A0_22a = __builtin_amdgcn_mfma_f32_16x16x32_bf16(bfr[ 8 + ks], af0A, A0_22a, 0, 0, 0);
            B0_22a = __builtin_amdgcn_mfma_f32_16x16x32_bf16(bfr[ 8 + ks], af0B, B0_22a, 0, 0, 0);
            A1_22a = __builtin_amdgcn_mfma_f32_16x16x32_bf16(bfr[ 8 + ks], af1A, A1_22a, 0, 0, 0);
            B1_22a = __builtin_amdgcn_mfma_f32_16x16x32_bf16(bfr[ 8 + ks], af1B, B1_22a, 0, 0, 0);
            A0_22b = __builtin_amdgcn_mfma_f32_16x16x32_bf16(bfr[12 + ks], af0A, A0_22b, 0, 0, 0);
            B0_22b = __builtin_amdgcn_mfma_f32_16x16x32_bf16(bfr[12 + ks], af0B, B0_22b, 0, 0, 0);
            A1_22b = __builtin_amdgcn_mfma_f32_16x16x32_bf16(bfr[12 + ks], af1A, A1_22b, 0, 0, 0);
            B1_22b = __builtin_amdgcn_mfma_f32_16x16x32_bf16(bfr[12 + ks], af1B, B1_22b, 0, 0, 0);
        }

        // heads: relu+pack into sigma-ordered B-fragments, 2 MFMA per chain
        f32x4 ini = {hb0, hb1, hb2, hb3};
        {
            uint4 h1, h2;
            h1.x = pk_bf16(fmaxf(A0_21a[0], 0.f), fmaxf(A0_21a[1], 0.f));
            h1.y = pk_bf16(fmaxf(A0_21a[2], 0.f), fmaxf(A0_21a[3], 0.f));
            h1.z = pk_bf16(fmaxf(A0_21b[0], 0.f), fmaxf(A0_21b[1], 0.f));
            h1.w = pk_bf16(fmaxf(A0_21b[2], 0.f), fmaxf(A0_21b[3], 0.f));
            h2.x = pk_bf16(fmaxf(A0_22a[0], 0.f), fmaxf(A0_22a[1], 0.f));
            h2.y = pk_bf16(fmaxf(A0_22a[2], 0.f), fmaxf(A0_22a[3], 0.f));
            h2.z = pk_bf16(fmaxf(A0_22b[0], 0.f), fmaxf(A0_22b[1], 0.f));
            h2.w = pk_bf16(fmaxf(A0_22b[2], 0.f), fmaxf(A0_22b[3], 0.f));
            hd0A = __builtin_amdgcn_mfma_f32_16x16x32_bf16(hfr0, as_s8(h1), ini, 0, 0, 0);
            hd0A = __builtin_amdgcn_mfma_f32_16x16x32_bf16(hfr1, as_s8(h2), hd0A, 0, 0, 0);
        }
        {
            uint4 h1, h2;
            h1.x = pk_bf16(fmaxf(B0_21a[0], 0.f), fmaxf(B0_21a[1], 0.f));
            h1.y = pk_bf16(fmaxf(B0_21a[2], 0.f), fmaxf(B0_21a[3], 0.f));
            h1.z = pk_bf16(fmaxf(B0_21b[0], 0.f), fmaxf(B0_21b[1], 0.f));
            h1.w = pk_bf16(fmaxf(B0_21b[2], 0.f), fmaxf(B0_21b[3], 0.f));
            h2.x = pk_bf16(fmaxf(B0_22a[0], 0.f), fmaxf(B0_22a[1], 0.f));
            h2.y = pk_bf16(fmaxf(B0_22a[2], 0.f), fmaxf(B0_22a[3], 0.f));
            h2.z = pk_bf16(fmaxf(B0_22b[0], 0.f), fmaxf(B0_22b[1], 0.f));
            h2.w = pk_bf16(fmaxf(B0_22b[2], 0.f), fmaxf(B0_22b[3], 0.f));
            hd0B = __builtin_amdgcn_mfma_f32_16x16x32_bf16(hfr0, as_s8(h1), ini, 0, 0, 0);
            hd0B = __builtin_amdgcn_mfma_f32_16x16x32_bf16(hfr1, as_s8(h2), hd0B, 0, 0, 0);
        }
        {
            uint4 h1, h2;
            h1.x = pk_bf16(fmaxf(A1_21a[0], 0.f), fmaxf(A1_21a[1], 0.f));
            h1.y = pk_bf16(fmaxf(A1_21a[2], 0.f), fmaxf(A1_21a[3], 0.f));
            h1.z = pk_bf16(fmaxf(A1_21b[0], 0.f), fmaxf(A1_21b[1], 0.f));
            h1.w = pk_bf16(fmaxf(A1_21b[2], 0.f), fmaxf(A1_21b[3], 0.f));
            h2.x = pk_bf16(fmaxf(A1_22a[0], 0.f), fmaxf(A1_22a[1], 0.f));
            h2.y = pk_bf16(fmaxf(A1_22a[2], 0.f), fmaxf(A1_22a[3], 0.f));
            h2.z = pk_bf16(fmaxf(A1_22b[0], 0.f), fmaxf(A1_22b[1], 0.f));
            h2.w = pk_bf16(fmaxf(A1_22b[2], 0.f), fmaxf(A1_22b[3], 0.f));
            hd1A = __builtin_amdgcn_mfma_f32_16x16x32_bf16(hfr0, as_s8(h1), ini, 0, 0, 0);
            hd1A = __builtin_amdgcn_mfma_f32_16x16x32_bf16(hfr1, as_s8(h2), hd1A, 0, 0, 0);
        }
        {
            uint4 h1, h2;
            h1.x = pk_bf16(fmaxf(B1_21a[0], 0.f), fmaxf(B1_21a[1], 0.f));
            h1.y = pk_bf16(fmaxf(B1_21a[2], 0.f), fmaxf(B1_21a[3], 0.f));
            h1.z = pk_bf16(fmaxf(B1_21b[0], 0.f), fmaxf(B1_21b[1], 0.f));
            h1.w = pk_bf16(fmaxf(B1_21b[2], 0.f), fmaxf(B1_21b[3], 0.f));
            h2.x = pk_bf16(fmaxf(B1_22a[0], 0.f), fmaxf(B1_22a[1], 0.f));
            h2.y = pk_bf16(fmaxf(B1_22a[2], 0.f), fmaxf(B1_22a[3], 0.f));
            h2.z = pk_bf16(fmaxf(B1_22b[0], 0.f), fmaxf(B1_22b[1], 0.f));
            h2.w = pk_bf16(fmaxf(B1_22b[2], 0.f), fmaxf(B1_22b[3], 0.f));
            hd1B = __builtin_amdgcn_mfma_f32_16x16x32_bf16(hfr0, as_s8(h1), ini, 0, 0, 0);
            hd1B = __builtin_amdgcn_mfma_f32_16x16x32_bf16(hfr1, as_s8(h2), hd1B, 0, 0, 0);
        }
        __builtin_amdgcn_s_setprio(0);
    };

    auto EPI = [&](int p, const float xA[5], const float xB[5],
                   const f32x4& hdA, const f32x4& hdB) {
        float hs0 = __shfl(hdB[0], r15);
        float hs1 = __shfl(hdB[1], r15);
        float hs2 = __shfl(hdB[2], r15);
        float hs3 = __shfl(hdB[3], r15);
        if (lane < 32) {
            const bool sa = (lane < 16);
            float x31_0 = sa ? hdA[0] : hs0;
            float x31_1 = sa ? hdA[1] : hs1;
            float t32_0 = sa ? hdA[2] : hs2;
            float t32_1 = sa ? hdA[3] : hs3;

            float s0v = __fdividef(4.f, 1.f + __expf(-t32_0));
            float s1v = __fdividef(4.f, 1.f + __expf(-t32_1));
            float hcoef = s0v * s1v;

            float xo[5];
            #pragma unroll
            for (int c = 0; c < 5; ++c) {
                float m = meanp[c], s = stdp[c];
                float xc = sa ? xA[c] : xB[c];
                float x0 = fmaf(xc, s, m);
                xo[c] = fmaf(x0, s, m);
            }
            float px = xo[0], py = xo[1], th = xo[2], oppx = xo[3], oppy = xo[4];
            float st, ct;
            __sincosf(th, &st, &ct);

            float upper = INFINITY, lower = -INFINITY;
            #pragma unroll
            for (int j = 0; j < 9; ++j) {
                float ox, oy, rr2;
                if (j < 8) {
                    ox = obstacles[j * 3];
                    oy = obstacles[j * 3 + 1];
                    float rr = obstacles[j * 3 + 2];
                    rr2 = rr * rr;
                } else {
                    ox = oppx; oy = oppy; rr2 = 0.3f * 0.3f;
                }
                float dx = px - ox, dy = py - oy;
                float bar = fmaf(dx, dx, fmaf(dy, dy, -rr2));
                float g1  = -2.f * fmaf(dx, ct, dy * st);
                float ratio = __fdividef(hcoef * bar, (g1 != 0.f) ? g1 : 1.f);
                if (g1 > 0.f) upper = fminf(upper, ratio);
                if (g1 < 0.f) lower = fmaxf(lower, ratio);
            }
            float u1 = fminf(fmaxf(-x31_0, lower), upper);
            float u2 = -x31_1;

            int row = p * 32 + lane;
            if (row < nB) {
                float2 o; o.x = u1; o.y = u2;
                *reinterpret_cast<float2*>(out + 2 * (size_t)row) = o;
            }
        }
    };

    // ---- straight-line 4 pairs: MLP4(0,1) -> EPI(0) -> MLP4(2,3) -> EPI(1..3)
    const int P0 = wid;
    const int P1 = wid + nwaves;
    const int P2 = wid + 2 * nwaves;
    const int P3 = wid + 3 * nwaves;

    float x0A[5], x0B[5], x1A[5], x1B[5], x2A[5], x2B[5], x3A[5], x3B[5];
    LOADX(P0, x0A, x0B);
    LOADX(P1, x1A, x1B);
    f32x4 hd0A, hd0B, hd1A, hd1B, hd2A, hd2B, hd3A, hd3B;
    MLP4(x0A, x0B, x1A, x1B, hd0A, hd0B, hd1A, hd1B);
    LOADX(P2, x2A, x2B);
    LOADX(P3, x3A, x3B);
    EPI(P0, x0A, x0B, hd0A, hd0B);
    MLP4(x2A, x2B, x3A, x3B, hd2A, hd2B, hd3A, hd3B);
    EPI(P1, x1A, x1B, hd1A, hd1B);
    EPI(P2, x2A, x2B, hd2A, hd2B);
    EPI(P3, x3A, x3B, hd3A, hd3B);
}

extern "C" void kernel_launch(void* const* d_in, const int* in_sizes, int n_in,
                              void* d_out, int out_size, void* d_ws, size_t ws_size,
                              hipStream_t stream) {
    const float* x         = (const float*)d_in[0];
    const float* meanp     = (const float*)d_in[1];
    const float* stdp      = (const float*)d_in[2];
    const float* W1        = (const float*)d_in[3];
    const float* b1        = (const float*)d_in[4];
    const float* W21       = (const float*)d_in[5];
    const float* b21       = (const float*)d_in[6];
    const float* W22       = (const float*)d_in[7];
    const float* b22       = (const float*)d_in[8];
    const float* W31       = (const float*)d_in[9];
    const float* b31       = (const float*)d_in[10];
    const float* W32       = (const float*)d_in[11];
    const float* b32       = (const float*)d_in[12];
    const float* obstacles = (const float*)d_in[13];
    float* out = (float*)d_out;

    int nB = in_sizes[0] / 5;
    bnet<<<GRID, BLOCK, 0, stream>>>(
        x, meanp, stdp, W1, b1, W21, b21, W22, b22,
        W31, b31, W32, b32, obstacles, out, nB);
}

// Round 18
// 18.252 us; speedup vs baseline: 1.1520x; 1.0364x over previous
//
#include <hip/hip_runtime.h>
#include <math.h>

typedef __attribute__((ext_vector_type(8))) short short8v;
typedef __attribute__((ext_vector_type(4))) float f32x4;

#define BLOCK 512
#define GRID  256

__device__ inline unsigned int pk_bf16(float lo, float hi) {
    unsigned int r;
    asm("v_cvt_pk_bf16_f32 %0, %1, %2" : "=v"(r) : "v"(lo), "v"(hi));
    return r;
}
__device__ inline short8v as_s8(uint4 v) { union { uint4 u; short8v s; } c; c.u = v; return c.s; }
__device__ inline f32x4 as_f4(float4 v) { union { float4 u; f32x4 s; } c; c.u = v; return c.s; }

__global__ __launch_bounds__(BLOCK, 2) void bnet(
    const float* __restrict__ x,
    const float* __restrict__ meanp, const float* __restrict__ stdp,
    const float* __restrict__ W1,  const float* __restrict__ b1,
    const float* __restrict__ W21, const float* __restrict__ b21,
    const float* __restrict__ W22, const float* __restrict__ b22,
    const float* __restrict__ W31, const float* __restrict__ b31,
    const float* __restrict__ W32, const float* __restrict__ b32,
    const float* __restrict__ obstacles,
    float* __restrict__ out, int nB)
{
    // Layer-1 A-frags: [g*64+lane]; lanes<16 hold W1 row 16g+m (k=0..4 w, k=5 b1).
    __shared__ uint4 w1frag[8 * 64];                  // 8 KB
    // Layer-2 A-frags with pi-permuted K (verified rounds 4..17).
    __shared__ uint4 fragB[16 * 64];                  // 16 KB
    // Head A-frags (verified round 6/9/12): sigma-permuted W31/W32 rows.
    __shared__ uint4 headA[2 * 64];                   // 2 KB
    __shared__ float b2s[64];                         // b21[32] | b22[32]

    const int t = threadIdx.x;

    {   // zero w1frag (lanes >=16 must be zero); 512 threads cover 512 entries
        uint4 z = {0u, 0u, 0u, 0u};
        w1frag[t] = z;
    }
    __syncthreads();
    if (t < 128) {   // W1 fragments
        int m = t & 15, g = t >> 4;
        int u = 16 * g + m;
        const float* wr = W1 + u * 5;
        uint4 v;
        v.x = pk_bf16(wr[0], wr[1]);
        v.y = pk_bf16(wr[2], wr[3]);
        v.z = pk_bf16(wr[4], b1[u]);
        v.w = 0u;
        w1frag[g * 64 + m] = v;
    } else if (t < 256) {   // head A-fragments (threads 128..255) - verified
        int e  = t - 128;
        int ks = e >> 6, l = e & 63, m = l & 15, qq = l >> 4;
        float v[8];
        #pragma unroll
        for (int j = 0; j < 8; ++j) {
            int u = 16 * ((j >> 2) & 1) + 4 * qq + (j & 3);   // sigma^-1
            float val = 0.f;
            if (m == 0 && ks == 0) val = W31[u];
            if (m == 1 && ks == 0) val = W31[32 + u];
            if (m == 2 && ks == 1) val = W32[u];
            if (m == 3 && ks == 1) val = W32[32 + u];
            v[j] = val;
        }
        uint4 h;
        h.x = pk_bf16(v[0], v[1]); h.y = pk_bf16(v[2], v[3]);
        h.z = pk_bf16(v[4], v[5]); h.w = pk_bf16(v[6], v[7]);
        headA[ks * 64 + l] = h;
    }
    if (t < 64) b2s[t] = (t < 32) ? b21[t] : b22[t - 32];
    {   // layer-2 fragments (verified mapping); 512 threads x 2 iters = 1024
        const float4* w21v = (const float4*)W21;
        const float4* w22v = (const float4*)W22;
        #pragma unroll
        for (int e = 0; e < 2; ++e) {
            int g4   = t + e * 512;
            int uo   = g4 >> 5;
            int h0   = (g4 & 31) << 2;
            int ks   = h0 >> 5;
            int jh   = (h0 >> 4) & 1;
            int qq   = (h0 >> 2) & 3;
            int ln   = (qq << 4) | (uo & 15);
            int half = uo >> 4;
            float4 f1 = w21v[g4];
            float4 f2 = w22v[g4];
            unsigned int* dA = (unsigned int*)&fragB[(half * 4 + ks) * 64 + ln];
            unsigned int* dB = (unsigned int*)&fragB[(8 + half * 4 + ks) * 64 + ln];
            dA[jh * 2] = pk_bf16(f1.x, f1.y); dA[jh * 2 + 1] = pk_bf16(f1.z, f1.w);
            dB[jh * 2] = pk_bf16(f2.x, f2.y); dB[jh * 2 + 1] = pk_bf16(f2.z, f2.w);
        }
    }
    __syncthreads();

    const int lane = t & 63;
    const int q    = lane >> 4;
    const int r15  = lane & 15;
    const int wid    = blockIdx.x * 8 + (t >> 6);
    const int nwaves = GRID * 8;
    const int npairs = (nB + 31) >> 5;
    if (wid >= npairs) return;

    // Resident: W2 fragments (64 VGPR) + head A-frags (8 VGPR).
    short8v bfr[16];
    #pragma unroll
    for (int i = 0; i < 16; ++i) bfr[i] = as_s8(fragB[i * 64 + lane]);
    const short8v hfr0 = as_s8(headA[lane]);
    const short8v hfr1 = as_s8(headA[64 + lane]);
    const float4* b2v = (const float4*)b2s;

    const float hb0 = b31[0], hb1 = b31[1], hb2 = b32[0], hb3 = b32[1];

    auto LOADX = [&](int p, float xA[5], float xB[5]) {
        int rA = p * 32 + r15;      if (rA >= nB) rA = nB - 1;
        int rB = p * 32 + 16 + r15; if (rB >= nB) rB = nB - 1;
        const float* pA = x + (size_t)rA * 5;
        const float* pB = x + (size_t)rB * 5;
        #pragma unroll
        for (int c = 0; c < 5; ++c) { xA[c] = pA[c]; xB[c] = pB[c]; }
    };

    // MLP for TWO 32-row pairs (4 independent 16-row chains), R14 verbatim,
    // wrapped in s_setprio(1)/(0) (T5, verified R17 +2.8%).
    auto MLP4 = [&](const float xA0[5], const float xB0[5],
                    const float xA1[5], const float xB1[5],
                    f32x4& hd0A, f32x4& hd0B, f32x4& hd1A, f32x4& hd1B) {
        uint4 t0a, t0b, t1a, t1b;
        t0a.x = pk_bf16(xA0[0], xA0[1]); t0a.y = pk_bf16(xA0[2], xA0[3]);
        t0a.z = pk_bf16(xA0[4], 1.0f);   t0a.w = 0u;
        t0b.x = pk_bf16(xB0[0], xB0[1]); t0b.y = pk_bf16(xB0[2], xB0[3]);
        t0b.z = pk_bf16(xB0[4], 1.0f);   t0b.w = 0u;
        t1a.x = pk_bf16(xA1[0], xA1[1]); t1a.y = pk_bf16(xA1[2], xA1[3]);
        t1a.z = pk_bf16(xA1[4], 1.0f);   t1a.w = 0u;
        t1b.x = pk_bf16(xB1[0], xB1[1]); t1b.y = pk_bf16(xB1[2], xB1[3]);
        t1b.z = pk_bf16(xB1[4], 1.0f);   t1b.w = 0u;
        short8v xf0A = as_s8(t0a), xf0B = as_s8(t0b);
        short8v xf1A = as_s8(t1a), xf1B = as_s8(t1b);

        f32x4 i0 = as_f4(b2v[q]),     i1 = as_f4(b2v[4 + q]);
        f32x4 i2 = as_f4(b2v[8 + q]), i3 = as_f4(b2v[12 + q]);
        f32x4 A0_21a = i0, A0_21b = i1, A0_22a = i2, A0_22b = i3;
        f32x4 B0_21a = i0, B0_21b = i1, B0_22a = i2, B0_22b = i3;
        f32x4 A1_21a = i0, A1_21b = i1, A1_22a = i2, A1_22b = i3;
        f32x4 B1_21a = i0, B1_21b = i1, B1_22a = i2, B1_22b = i3;

        __builtin_amdgcn_s_setprio(1);
        #pragma unroll
        for (int ks = 0; ks < 4; ++ks) {
            f32x4 z = {0.f, 0.f, 0.f, 0.f};
            short8v w0  = as_s8(w1frag[(2 * ks) * 64 + lane]);
            short8v w1v = as_s8(w1frag[(2 * ks + 1) * 64 + lane]);
            f32x4 u0A = __builtin_amdgcn_mfma_f32_16x16x32_bf16(w0,  xf0A, z, 0, 0, 0);
            f32x4 v0A = __builtin_amdgcn_mfma_f32_16x16x32_bf16(w1v, xf0A, z, 0, 0, 0);
            f32x4 u0B = __builtin_amdgcn_mfma_f32_16x16x32_bf16(w0,  xf0B, z, 0, 0, 0);
            f32x4 v0B = __builtin_amdgcn_mfma_f32_16x16x32_bf16(w1v, xf0B, z, 0, 0, 0);
            f32x4 u1A = __builtin_amdgcn_mfma_f32_16x16x32_bf16(w0,  xf1A, z, 0, 0, 0);
            f32x4 v1A = __builtin_amdgcn_mfma_f32_16x16x32_bf16(w1v, xf1A, z, 0, 0, 0);
            f32x4 u1B = __builtin_amdgcn_mfma_f32_16x16x32_bf16(w0,  xf1B, z, 0, 0, 0);
            f32x4 v1B = __builtin_amdgcn_mfma_f32_16x16x32_bf16(w1v, xf1B, z, 0, 0, 0);
            uint4 pa, pb, pc, pd;
            pa.x = pk_bf16(fmaxf(u0A[0], 0.f), fmaxf(u0A[1], 0.f));
            pa.y = pk_bf16(fmaxf(u0A[2], 0.f), fmaxf(u0A[3], 0.f));
            pa.z = pk_bf16(fmaxf(v0A[0], 0.f), fmaxf(v0A[1], 0.f));
            pa.w = pk_bf16(fmaxf(v0A[2], 0.f), fmaxf(v0A[3], 0.f));
            pb.x = pk_bf16(fmaxf(u0B[0], 0.f), fmaxf(u0B[1], 0.f));
            pb.y = pk_bf16(fmaxf(u0B[2], 0.f), fmaxf(u0B[3], 0.f));
            pb.z = pk_bf16(fmaxf(v0B[0], 0.f), fmaxf(v0B[1], 0.f));
            pb.w = pk_bf16(fmaxf(v0B[2], 0.f), fmaxf(v0B[3], 0.f));
            pc.x = pk_bf16(fmaxf(u1A[0], 0.f), fmaxf(u1A[1], 0.f));
            pc.y = pk_bf16(fmaxf(u1A[2], 0.f), fmaxf(u1A[3], 0.f));
            pc.z = pk_bf16(fmaxf(v1A[0], 0.f), fmaxf(v1A[1], 0.f));
            pc.w = pk_bf16(fmaxf(v1A[2], 0.f), fmaxf(v1A[3], 0.f));
            pd.x = pk_bf16(fmaxf(u1B[0], 0.f), fmaxf(u1B[1], 0.f));
            pd.y = pk_bf16(fmaxf(u1B[2], 0.f), fmaxf(u1B[3], 0.f));
            pd.z = pk_bf16(fmaxf(v1B[0], 0.f), fmaxf(v1B[1], 0.f));
            pd.w = pk_bf16(fmaxf(v1B[2], 0.f), fmaxf(v1B[3], 0.f));
            short8v af0A = as_s8(pa), af0B = as_s8(pb);
            short8v af1A = as_s8(pc), af1B = as_s8(pd);
            A0_21a = __builtin_amdgcn_mfma_f32_16x16x32_bf16(bfr[     ks], af0A, A0_21a, 0, 0, 0);
            B0_21a = __builtin_amdgcn_mfma_f32_16x16x32_bf16(bfr[     ks], af0B, B0_21a, 0, 0, 0);
            A1_21a = __builtin_amdgcn_mfma_f32_16x16x32_bf16(bfr[     ks], af1A, A1_21a, 0, 0, 0);
            B1_21a = __builtin_amdgcn_mfma_f32_16x16x32_bf16(bfr[     ks], af1B, B1_21a, 0, 0, 0);
            A0_21b = __builtin_amdgcn_mfma_f32_16x16x32_bf16(bfr[ 4 + ks], af0A, A0_21b, 0, 0, 0);
            B0_21b = __builtin_amdgcn_mfma_f32_16x16x32_bf16(bfr[ 4 + ks], af0B, B0_21b, 0, 0, 0);
            A1_21b = __builtin_amdgcn_mfma_f32_16x16x32_bf16(bfr[ 4 + ks], af1A, A1_21b, 0, 0, 0);
            B1_21b = __builtin_amdgcn_mfma_f32_16x16x32_bf16(bfr[ 4 + ks], af1B, B1_21b, 0, 0, 0);
            A0_22a = __builtin_amdgcn_mfma_f32_16x16x32_bf16(bfr[ 8 + ks], af0A, A0_22a, 0, 0, 0);
            B0_22a = __builtin_amdgcn_mfma_f32_16x16x32_bf16(bfr[ 8 + ks], af0B, B0_22a, 0, 0, 0);
            A1_22a = __builtin_amdgcn_mfma_f32_16x16x32_bf16(bfr[ 8 + ks], af1A, A1_22a, 0, 0, 0);
            B1_22a = __builtin_amdgcn_mfma_f32_16x16x32_bf16(bfr[ 8 + ks], af1B, B1_22a, 0, 0, 0);
            A0_22b = __builtin_amdgcn_mfma_f32_16x16x32_bf16(bfr[12 + ks], af0A, A0_22b, 0, 0, 0);
            B0_22b = __builtin_amdgcn_mfma_f32_16x16x32_bf16(bfr[12 + ks], af0B, B0_22b, 0, 0, 0);
            A1_22b = __builtin_amdgcn_mfma_f32_16x16x32_bf16(bfr[12 + ks], af1A, A1_22b, 0, 0, 0);
            B1_22b = __builtin_amdgcn_mfma_f32_16x16x32_bf16(bfr[12 + ks], af1B, B1_22b, 0, 0, 0);
        }

        f32x4 ini = {hb0, hb1, hb2, hb3};
        {
            uint4 h1, h2;
            h1.x = pk_bf16(fmaxf(A0_21a[0], 0.f), fmaxf(A0_21a[1], 0.f));
            h1.y = pk_bf16(fmaxf(A0_21a[2], 0.f), fmaxf(A0_21a[3], 0.f));
            h1.z = pk_bf16(fmaxf(A0_21b[0], 0.f), fmaxf(A0_21b[1], 0.f));
            h1.w = pk_bf16(fmaxf(A0_21b[2], 0.f), fmaxf(A0_21b[3], 0.f));
            h2.x = pk_bf16(fmaxf(A0_22a[0], 0.f), fmaxf(A0_22a[1], 0.f));
            h2.y = pk_bf16(fmaxf(A0_22a[2], 0.f), fmaxf(A0_22a[3], 0.f));
            h2.z = pk_bf16(fmaxf(A0_22b[0], 0.f), fmaxf(A0_22b[1], 0.f));
            h2.w = pk_bf16(fmaxf(A0_22b[2], 0.f), fmaxf(A0_22b[3], 0.f));
            hd0A = __builtin_amdgcn_mfma_f32_16x16x32_bf16(hfr0, as_s8(h1), ini, 0, 0, 0);
            hd0A = __builtin_amdgcn_mfma_f32_16x16x32_bf16(hfr1, as_s8(h2), hd0A, 0, 0, 0);
        }
        {
            uint4 h1, h2;
            h1.x = pk_bf16(fmaxf(B0_21a[0], 0.f), fmaxf(B0_21a[1], 0.f));
            h1.y = pk_bf16(fmaxf(B0_21a[2], 0.f), fmaxf(B0_21a[3], 0.f));
            h1.z = pk_bf16(fmaxf(B0_21b[0], 0.f), fmaxf(B0_21b[1], 0.f));
            h1.w = pk_bf16(fmaxf(B0_21b[2], 0.f), fmaxf(B0_21b[3], 0.f));
            h2.x = pk_bf16(fmaxf(B0_22a[0], 0.f), fmaxf(B0_22a[1], 0.f));
            h2.y = pk_bf16(fmaxf(B0_22a[2], 0.f), fmaxf(B0_22a[3], 0.f));
            h2.z = pk_bf16(fmaxf(B0_22b[0], 0.f), fmaxf(B0_22b[1], 0.f));
            h2.w = pk_bf16(fmaxf(B0_22b[2], 0.f), fmaxf(B0_22b[3], 0.f));
            hd0B = __builtin_amdgcn_mfma_f32_16x16x32_bf16(hfr0, as_s8(h1), ini, 0, 0, 0);
            hd0B = __builtin_amdgcn_mfma_f32_16x16x32_bf16(hfr1, as_s8(h2), hd0B, 0, 0, 0);
        }
        {
            uint4 h1, h2;
            h1.x = pk_bf16(fmaxf(A1_21a[0], 0.f), fmaxf(A1_21a[1], 0.f));
            h1.y = pk_bf16(fmaxf(A1_21a[2], 0.f), fmaxf(A1_21a[3], 0.f));
            h1.z = pk_bf16(fmaxf(A1_21b[0], 0.f), fmaxf(A1_21b[1], 0.f));
            h1.w = pk_bf16(fmaxf(A1_21b[2], 0.f), fmaxf(A1_21b[3], 0.f));
            h2.x = pk_bf16(fmaxf(A1_22a[0], 0.f), fmaxf(A1_22a[1], 0.f));
            h2.y = pk_bf16(fmaxf(A1_22a[2], 0.f), fmaxf(A1_22a[3], 0.f));
            h2.z = pk_bf16(fmaxf(A1_22b[0], 0.f), fmaxf(A1_22b[1], 0.f));
            h2.w = pk_bf16(fmaxf(A1_22b[2], 0.f), fmaxf(A1_22b[3], 0.f));
            hd1A = __builtin_amdgcn_mfma_f32_16x16x32_bf16(hfr0, as_s8(h1), ini, 0, 0, 0);
            hd1A = __builtin_amdgcn_mfma_f32_16x16x32_bf16(hfr1, as_s8(h2), hd1A, 0, 0, 0);
        }
        {
            uint4 h1, h2;
            h1.x = pk_bf16(fmaxf(B1_21a[0], 0.f), fmaxf(B1_21a[1], 0.f));
            h1.y = pk_bf16(fmaxf(B1_21a[2], 0.f), fmaxf(B1_21a[3], 0.f));
            h1.z = pk_bf16(fmaxf(B1_21b[0], 0.f), fmaxf(B1_21b[1], 0.f));
            h1.w = pk_bf16(fmaxf(B1_21b[2], 0.f), fmaxf(B1_21b[3], 0.f));
            h2.x = pk_bf16(fmaxf(B1_22a[0], 0.f), fmaxf(B1_22a[1], 0.f));
            h2.y = pk_bf16(fmaxf(B1_22a[2], 0.f), fmaxf(B1_22a[3], 0.f));
            h2.z = pk_bf16(fmaxf(B1_22b[0], 0.f), fmaxf(B1_22b[1], 0.f));
            h2.w = pk_bf16(fmaxf(B1_22b[2], 0.f), fmaxf(B1_22b[3], 0.f));
            hd1B = __builtin_amdgcn_mfma_f32_16x16x32_bf16(hfr0, as_s8(h1), ini, 0, 0, 0);
            hd1B = __builtin_amdgcn_mfma_f32_16x16x32_bf16(hfr1, as_s8(h2), hd1B, 0, 0, 0);
        }
        __builtin_amdgcn_s_setprio(0);
    };

    auto EPI = [&](int p, const float xA[5], const float xB[5],
                   const f32x4& hdA, const f32x4& hdB) {
        float hs0 = __shfl(hdB[0], r15);
        float hs1 = __shfl(hdB[1], r15);
        float hs2 = __shfl(hdB[2], r15);
        float hs3 = __shfl(hdB[3], r15);
        if (lane < 32) {
            const bool sa = (lane < 16);
            float x31_0 = sa ? hdA[0] : hs0;
            float x31_1 = sa ? hdA[1] : hs1;
            float t32_0 = sa ? hdA[2] : hs2;
            float t32_1 = sa ? hdA[3] : hs3;

            float s0v = __fdividef(4.f, 1.f + __expf(-t32_0));
            float s1v = __fdividef(4.f, 1.f + __expf(-t32_1));
            float hcoef = s0v * s1v;

            float xo[5];
            #pragma unroll
            for (int c = 0; c < 5; ++c) {
                float m = meanp[c], s = stdp[c];
                float xc = sa ? xA[c] : xB[c];
                float x0 = fmaf(xc, s, m);
                xo[c] = fmaf(x0, s, m);
            }
            float px = xo[0], py = xo[1], th = xo[2], oppx = xo[3], oppy = xo[4];
            float st, ct;
            __sincosf(th, &st, &ct);

            float upper = INFINITY, lower = -INFINITY;
            #pragma unroll
            for (int j = 0; j < 9; ++j) {
                float ox, oy, rr2;
                if (j < 8) {
                    ox = obstacles[j * 3];
                    oy = obstacles[j * 3 + 1];
                    float rr = obstacles[j * 3 + 2];
                    rr2 = rr * rr;
                } else {
                    ox = oppx; oy = oppy; rr2 = 0.3f * 0.3f;
                }
                float dx = px - ox, dy = py - oy;
                float bar = fmaf(dx, dx, fmaf(dy, dy, -rr2));
                float g1  = -2.f * fmaf(dx, ct, dy * st);
                float ratio = __fdividef(hcoef * bar, (g1 != 0.f) ? g1 : 1.f);
                if (g1 > 0.f) upper = fminf(upper, ratio);
                if (g1 < 0.f) lower = fmaxf(lower, ratio);
            }
            float u1 = fminf(fmaxf(-x31_0, lower), upper);
            float u2 = -x31_1;

            int row = p * 32 + lane;
            if (row < nB) {
                float2 o; o.x = u1; o.y = u2;
                *reinterpret_cast<float2*>(out + 2 * (size_t)row) = o;
            }
        }
    };

    // ---- straight-line 4 pairs: MLP4(0,1) -> EPI(0) -> MLP4(2,3) -> EPI(1..3)
    const int P0 = wid;
    const int P1 = wid + nwaves;
    const int P2 = wid + 2 * nwaves;
    const int P3 = wid + 3 * nwaves;

    float x0A[5], x0B[5], x1A[5], x1B[5], x2A[5], x2B[5], x3A[5], x3B[5];
    LOADX(P0, x0A, x0B);
    LOADX(P1, x1A, x1B);
    f32x4 hd0A, hd0B, hd1A, hd1B, hd2A, hd2B, hd3A, hd3B;
    MLP4(x0A, x0B, x1A, x1B, hd0A, hd0B, hd1A, hd1B);
    LOADX(P2, x2A, x2B);
    LOADX(P3, x3A, x3B);
    EPI(P0, x0A, x0B, hd0A, hd0B);
    MLP4(x2A, x2B, x3A, x3B, hd2A, hd2B, hd3A, hd3B);
    EPI(P1, x1A, x1B, hd1A, hd1B);
    EPI(P2, x2A, x2B, hd2A, hd2B);
    EPI(P3, x3A, x3B, hd3A, hd3B);
}

extern "C" void kernel_launch(void* const* d_in, const int* in_sizes, int n_in,
                              void* d_out, int out_size, void* d_ws, size_t ws_size,
                              hipStream_t stream) {
    const float* x         = (const float*)d_in[0];
    const float* meanp     = (const float*)d_in[1];
    const float* stdp      = (const float*)d_in[2];
    const float* W1        = (const float*)d_in[3];
    const float* b1        = (const float*)d_in[4];
    const float* W21       = (const float*)d_in[5];
    const float* b21       = (const float*)d_in[6];
    const float* W22       = (const float*)d_in[7];
    const float* b22       = (const float*)d_in[8];
    const float* W31       = (const float*)d_in[9];
    const float* b31       = (const float*)d_in[10];
    const float* W32       = (const float*)d_in[11];
    const float* b32       = (const float*)d_in[12];
    const float* obstacles = (const float*)d_in[13];
    float* out = (float*)d_out;

    int nB = in_sizes[0] / 5;
    bnet<<<GRID, BLOCK, 0, stream>>>(
        x, meanp, stdp, W1, b1, W21, b21, W22, b22,
        W31, b31, W32, b32, obstacles, out, nB);
}